// Round 1
// baseline (2064.325 us; speedup 1.0000x reference)
//
#include <hip/hip_runtime.h>

// IntersiteModel fused kernel — fp32 vector, round 3.
// 1 thread = 1 sample. Per-thread scratch in LDS (feature-major, f*128+tid),
// 80 features * 4B * 128 thr = 40960 B/block -> exactly 4 blocks/CU.
//   staging:  f 0..15 x0 | f 16..39 x1[u][i] | f 40..55 y0 | f 56..79 y1[v][i]
//   stage1+:  f 0..31 t0 | f 32..79 t1[u][i]
//   stage3:   f 0..31 s  | f 32..63 v_i (one xyz component at a time)  <= 80 OK
// Round-3 changes vs round 2 (theory: s_load latency serialization at rolled
// loop-body boundaries, unhidden at 2 waves/SIMD):
//   * #pragma unroll 2/4 on all weight-contraction loops so the scheduler
//     software-pipelines the uniform (s_load) weight fetches.
//   * merged W1_11_0+W1_11_1 into one uv loop (shares 6 LDS reads + loop ctrl)
//   * merged W2_10+W2_11_1+W2_11_0 into one u loop (shares 3 LDS reads x3)
//     -> u0 is zero-initialized just before it (after W2_01, so A2 chunk loop
//        does not see u0 live; peak VGPR unchanged).

#define TPB 128

__device__ __forceinline__ float sigf(float x) {
    return 1.0f / (1.0f + __expf(-x));
}

__global__ __launch_bounds__(TPB, 2)
void intersite_fused(const float* __restrict__ site1,
                     const float* __restrict__ site2,
                     const float* __restrict__ edge,
                     const float* __restrict__ W1_00,
                     const float* __restrict__ W1_11_0,
                     const float* __restrict__ W1_01,
                     const float* __restrict__ W1_10,
                     const float* __restrict__ W1_11_1,
                     const float* __restrict__ W2_00,
                     const float* __restrict__ W2_11_0,
                     const float* __restrict__ W2_01,
                     const float* __restrict__ W2_10,
                     const float* __restrict__ W2_11_1,
                     const float* __restrict__ W3_00,
                     const float* __restrict__ W3_11,
                     float* __restrict__ out, int B)
{
    __shared__ float lds[80 * TPB];
    const int t = threadIdx.x;
    const int b = blockIdx.x * TPB + t;
    if (b >= B) return;   // no barriers anywhere -> early return is safe

#define LDSF(f) lds[(f) * TPB + t]

    const float inv_s3   = 0.57735026918962576f;  // 1/sqrt(3)
    const float inv_s2   = 0.70710678118654752f;  // 1/sqrt(2)
    const float inv_s320 = 0.05590169943749474f;  // 1/sqrt(320)
    const float inv_s192 = 0.07216878364870323f;  // 1/sqrt(192)
    const float inv_s256 = 0.0625f;               // 1/sqrt(256)
    const float inv_s2048= 0.02209708691207961f;  // 1/sqrt(2048)

    // ---------------- stage inputs into LDS ----------------
    {
        const float4* p1 = (const float4*)(site1 + (size_t)b * 40);
        #pragma unroll
        for (int q = 0; q < 10; ++q) {
            float4 r = p1[q];
            LDSF(q*4+0) = r.x; LDSF(q*4+1) = r.y;
            LDSF(q*4+2) = r.z; LDSF(q*4+3) = r.w;
        }
        const float4* p2 = (const float4*)(site2 + (size_t)b * 40);
        #pragma unroll
        for (int q = 0; q < 10; ++q) {
            float4 r = p2[q];
            LDSF(40+q*4+0) = r.x; LDSF(40+q*4+1) = r.y;
            LDSF(40+q*4+2) = r.z; LDSF(40+q*4+3) = r.w;
        }
    }
    // edge stays in registers (accessed only with unrolled v<=4 loops)
    float e0[4], e1[12];
    {
        const float4* pe = (const float4*)(edge + (size_t)b * 16);
        float4 r0 = pe[0], r1 = pe[1], r2 = pe[2], r3 = pe[3];
        e0[0]=r0.x; e0[1]=r0.y; e0[2]=r0.z; e0[3]=r0.w;
        e1[0]=r1.x; e1[1]=r1.y; e1[2]=r1.z; e1[3]=r1.w;
        e1[4]=r2.x; e1[5]=r2.y; e1[6]=r2.z; e1[7]=r2.w;
        e1[8]=r3.x; e1[9]=r3.y; e1[10]=r3.z; e1[11]=r3.w;
    }

    // ---------------- stage 1: (x,y) -> t0[32], t1[16][3] ----------------
    float t0[32];
    #pragma unroll
    for (int k = 0; k < 32; ++k) t0[k] = 0.0f;
    float t1[48];
    #pragma unroll
    for (int j = 0; j < 48; ++j) t1[j] = 0.0f;

    // W1_00 (16,16,32): sum_{u,v} x0[u] y0[v] W[u,v,w]
    #pragma unroll 1
    for (int u = 0; u < 16; ++u) {
        float xu = LDSF(u);
        const float* wu = W1_00 + u * 512;           // u*16*32
        #pragma unroll 4
        for (int v = 0; v < 16; ++v) {
            float f = xu * LDSF(40 + v);
            const float* w = wu + v * 32;
            #pragma unroll
            for (int k = 0; k < 32; ++k) t0[k] = fmaf(f, w[k], t0[k]);
        }
    }

    // merged W1_11_0 (8,8,32) + W1_11_1 (8,8,16): shares x1/y1 LDS reads.
    //   t0[w] += (x1[u].y1[v])/sqrt3 * W0[u,v,w]
    //   t1[w,i] += (x1[u] x y1[v])_i / sqrt2 * W1[u,v,w]
    #pragma unroll 2
    for (int uv = 0; uv < 64; ++uv) {
        int u = uv >> 3, v = uv & 7;
        float ax = LDSF(16+u*3), ay = LDSF(17+u*3), az = LDSF(18+u*3);
        float bx = LDSF(56+v*3), by = LDSF(57+v*3), bz = LDSF(58+v*3);
        float d = ax*bx;
        d = fmaf(ay, by, d);
        d = fmaf(az, bz, d);
        d *= inv_s3;
        const float* w0 = W1_11_0 + uv * 32;
        #pragma unroll
        for (int k = 0; k < 32; ++k) t0[k] = fmaf(d, w0[k], t0[k]);
        float cx = (ay*bz - az*by) * inv_s2;
        float cy = (az*bx - ax*bz) * inv_s2;
        float cz = (ax*by - ay*bx) * inv_s2;
        const float* w1 = W1_11_1 + uv * 16;
        #pragma unroll
        for (int k = 0; k < 16; ++k) {
            t1[k*3+0] = fmaf(cx, w1[k], t1[k*3+0]);
            t1[k*3+1] = fmaf(cy, w1[k], t1[k*3+1]);
            t1[k*3+2] = fmaf(cz, w1[k], t1[k*3+2]);
        }
    }
    #pragma unroll
    for (int k = 0; k < 32; ++k) t0[k] *= inv_s320;

    // W1_01 (16,8,16) factored: A[v,w] = sum_u x0[u] W[u,v,w]; t1 += A y1
    {
        float yr[24];
        #pragma unroll
        for (int v = 0; v < 8; ++v)
            #pragma unroll
            for (int i = 0; i < 3; ++i) yr[v*3+i] = LDSF(56 + v*3 + i);
        #pragma unroll            // FULL unroll: keeps t1 indices constant
        for (int wc = 0; wc < 2; ++wc) {      // w-chunks of 8
            float A[64];
            #pragma unroll
            for (int j = 0; j < 64; ++j) A[j] = 0.0f;
            #pragma unroll 2
            for (int u = 0; u < 16; ++u) {
                float xu = LDSF(u);
                const float* w = W1_01 + u*128 + wc*8;   // u*128 + v*16 + w
                #pragma unroll
                for (int v = 0; v < 8; ++v)
                    #pragma unroll
                    for (int k = 0; k < 8; ++k)
                        A[v*8+k] = fmaf(xu, w[v*16+k], A[v*8+k]);
            }
            #pragma unroll
            for (int v = 0; v < 8; ++v)
                #pragma unroll
                for (int k = 0; k < 8; ++k)
                    #pragma unroll
                    for (int i = 0; i < 3; ++i)
                        t1[(wc*8+k)*3+i] = fmaf(A[v*8+k], yr[v*3+i], t1[(wc*8+k)*3+i]);
        }
    }
    // W1_10 (8,16,16) factored: Bm[u,w] = sum_v y0[v] W[u,v,w]; t1 += Bm x1
    {
        float xr[24];
        #pragma unroll
        for (int u = 0; u < 8; ++u)
            #pragma unroll
            for (int i = 0; i < 3; ++i) xr[u*3+i] = LDSF(16 + u*3 + i);
        #pragma unroll            // FULL unroll
        for (int wc = 0; wc < 2; ++wc) {
            float Bm[64];
            #pragma unroll
            for (int j = 0; j < 64; ++j) Bm[j] = 0.0f;
            #pragma unroll 2
            for (int v = 0; v < 16; ++v) {
                float yv = LDSF(40 + v);
                const float* w = W1_10 + v*16 + wc*8;    // u*256 + v*16 + w
                #pragma unroll
                for (int u = 0; u < 8; ++u)
                    #pragma unroll
                    for (int k = 0; k < 8; ++k)
                        Bm[u*8+k] = fmaf(yv, w[u*256+k], Bm[u*8+k]);
            }
            #pragma unroll
            for (int u = 0; u < 8; ++u)
                #pragma unroll
                for (int k = 0; k < 8; ++k)
                    #pragma unroll
                    for (int i = 0; i < 3; ++i)
                        t1[(wc*8+k)*3+i] = fmaf(Bm[u*8+k], xr[u*3+i], t1[(wc*8+k)*3+i]);
        }
    }
    #pragma unroll
    for (int j = 0; j < 48; ++j) t1[j] *= inv_s320;

    // spill t into LDS (x/y region dead): f 0..31 = t0, f 32..79 = t1
    #pragma unroll
    for (int k = 0; k < 32; ++k) LDSF(k) = t0[k];
    #pragma unroll
    for (int j = 0; j < 48; ++j) LDSF(32 + j) = t1[j];

    // ---------------- stage 2: (t,e) -> u0[64], u1[32][3] ----------------
    float u1[96];
    #pragma unroll
    for (int j = 0; j < 96; ++j) u1[j] = 0.0f;

    // W2_01 (32,4,32) factored: A2[v,w] = sum_u t0[u] W[u,v,w]; u1 += A2 e1
    // (runs BEFORE u0 exists, so A2's 64 regs don't stack on u0's 64)
    #pragma unroll                // FULL unroll
    for (int wc = 0; wc < 2; ++wc) {          // w-chunks of 16
        float A2[64];
        #pragma unroll
        for (int j = 0; j < 64; ++j) A2[j] = 0.0f;
        #pragma unroll 2
        for (int u = 0; u < 32; ++u) {
            float tu = LDSF(u);
            const float* w = W2_01 + u*128 + wc*16;      // u*128 + v*32 + w
            #pragma unroll
            for (int v = 0; v < 4; ++v)
                #pragma unroll
                for (int k = 0; k < 16; ++k)
                    A2[v*16+k] = fmaf(tu, w[v*32+k], A2[v*16+k]);
        }
        #pragma unroll
        for (int v = 0; v < 4; ++v)
            #pragma unroll
            for (int k = 0; k < 16; ++k)
                #pragma unroll
                for (int i = 0; i < 3; ++i)
                    u1[(wc*16+k)*3+i] = fmaf(A2[v*16+k], e1[v*3+i], u1[(wc*16+k)*3+i]);
    }

    float u0[64];
    #pragma unroll
    for (int k = 0; k < 64; ++k) u0[k] = 0.0f;

    // merged W2_10 (16,4,32) + W2_11_1 (16,4,32) + W2_11_0 (16,4,64):
    // shares the 3 t1[u] LDS reads across all three contractions.
    #pragma unroll 1
    for (int u = 0; u < 16; ++u) {
        float ax = LDSF(32+u*3), ay = LDSF(33+u*3), az = LDSF(34+u*3);
        #pragma unroll
        for (int v = 0; v < 4; ++v) {
            float ev = e0[v];
            float f0 = ax*ev, f1 = ay*ev, f2 = az*ev;
            const float* wa = W2_10 + u*128 + v*32;
            #pragma unroll
            for (int k = 0; k < 32; ++k) {
                u1[k*3+0] = fmaf(f0, wa[k], u1[k*3+0]);
                u1[k*3+1] = fmaf(f1, wa[k], u1[k*3+1]);
                u1[k*3+2] = fmaf(f2, wa[k], u1[k*3+2]);
            }
            float bx = e1[v*3], by = e1[v*3+1], bz = e1[v*3+2];
            float cx = (ay*bz - az*by) * inv_s2;
            float cy = (az*bx - ax*bz) * inv_s2;
            float cz = (ax*by - ay*bx) * inv_s2;
            const float* wb = W2_11_1 + u*128 + v*32;
            #pragma unroll
            for (int k = 0; k < 32; ++k) {
                u1[k*3+0] = fmaf(cx, wb[k], u1[k*3+0]);
                u1[k*3+1] = fmaf(cy, wb[k], u1[k*3+1]);
                u1[k*3+2] = fmaf(cz, wb[k], u1[k*3+2]);
            }
            float dd = ax*bx;
            dd = fmaf(ay, by, dd);
            dd = fmaf(az, bz, dd);
            dd *= inv_s3;
            const float* wc = W2_11_0 + u*256 + v*64;
            #pragma unroll
            for (int k = 0; k < 64; ++k) u0[k] = fmaf(dd, wc[k], u0[k]);
        }
    }
    // W2_00 (32,4,64): u0[w] += t0[u] e0[v] W[u,v,w]
    #pragma unroll 2
    for (int u = 0; u < 32; ++u) {
        float tu = LDSF(u);
        #pragma unroll
        for (int v = 0; v < 4; ++v) {
            float f = tu * e0[v];
            const float* w = W2_00 + u*256 + v*64;
            #pragma unroll
            for (int k = 0; k < 64; ++k) u0[k] = fmaf(f, w[k], u0[k]);
        }
    }
    #pragma unroll
    for (int k = 0; k < 64; ++k) u0[k] *= inv_s192;
    #pragma unroll
    for (int j = 0; j < 96; ++j) u1[j] *= inv_s256;

    // ---------------- stage 3: gate + tensor square ----------------
    // s = silu(u0[:32]) -> LDS f 0..31 (t0 region dead)
    #pragma unroll
    for (int k = 0; k < 32; ++k) {
        float x = u0[k];
        LDSF(k) = x * sigf(x);
    }
    // v = u1 * sigmoid(u0[32:]) kept in registers (const-indexed)
    #pragma unroll
    for (int wv = 0; wv < 32; ++wv) {
        float gw = sigf(u0[32 + wv]);
        u1[wv*3+0] *= gw;  u1[wv*3+1] *= gw;  u1[wv*3+2] *= gw;
    }

    float acc0 = 0.0f, acc1 = 0.0f;
    // scalar part: acc0 = sum_{u,v2} s[u] s[v2] W3_00[u,v2]
    {
        float zs[32];
        #pragma unroll
        for (int k = 0; k < 32; ++k) zs[k] = 0.0f;
        #pragma unroll 2
        for (int u = 0; u < 32; ++u) {
            float su = LDSF(u);
            const float* wa = W3_00 + u*32;
            #pragma unroll
            for (int k = 0; k < 32; ++k) zs[k] = fmaf(su, wa[k], zs[k]);
        }
        #pragma unroll
        for (int k = 0; k < 32; ++k) acc0 = fmaf(zs[k], LDSF(k), acc0);
    }
    // vector part, ONE COMPONENT AT A TIME through LDS f 32..63 (bounds-safe):
    // acc1 = sum_i sum_{u,v2} v[u,i] v[v2,i] W3_11[u,v2]
    #pragma unroll
    for (int i = 0; i < 3; ++i) {
        #pragma unroll
        for (int wv = 0; wv < 32; ++wv) LDSF(32 + wv) = u1[wv*3 + i];
        float zv[32];
        #pragma unroll
        for (int k = 0; k < 32; ++k) zv[k] = 0.0f;
        #pragma unroll 2
        for (int u = 0; u < 32; ++u) {
            float vu = LDSF(32 + u);
            const float* wb = W3_11 + u*32;
            #pragma unroll
            for (int k = 0; k < 32; ++k) zv[k] = fmaf(vu, wb[k], zv[k]);
        }
        #pragma unroll
        for (int k = 0; k < 32; ++k) acc1 = fmaf(zv[k], LDSF(32 + k), acc1);
    }

    out[b] = (acc0 + acc1 * inv_s3) * inv_s2048;
#undef LDSF
}

extern "C" void kernel_launch(void* const* d_in, const int* in_sizes, int n_in,
                              void* d_out, int out_size, void* d_ws, size_t ws_size,
                              hipStream_t stream)
{
    const float* site1   = (const float*)d_in[0];
    const float* site2   = (const float*)d_in[1];
    const float* edge    = (const float*)d_in[2];
    const float* W1_00   = (const float*)d_in[3];
    const float* W1_11_0 = (const float*)d_in[4];
    const float* W1_01   = (const float*)d_in[5];
    const float* W1_10   = (const float*)d_in[6];
    const float* W1_11_1 = (const float*)d_in[7];
    const float* W2_00   = (const float*)d_in[8];
    const float* W2_11_0 = (const float*)d_in[9];
    const float* W2_01   = (const float*)d_in[10];
    const float* W2_10   = (const float*)d_in[11];
    const float* W2_11_1 = (const float*)d_in[12];
    const float* W3_00   = (const float*)d_in[13];
    const float* W3_11   = (const float*)d_in[14];
    float* out = (float*)d_out;

    const int B = in_sizes[0] / 40;
    dim3 grid((B + TPB - 1) / TPB), block(TPB);
    hipLaunchKernelGGL(intersite_fused, grid, block, 0, stream,
                       site1, site2, edge,
                       W1_00, W1_11_0, W1_01, W1_10, W1_11_1,
                       W2_00, W2_11_0, W2_01, W2_10, W2_11_1,
                       W3_00, W3_11, out, B);
}

// Round 2
// 1946.952 us; speedup vs baseline: 1.0603x; 1.0603x over previous
//
#include <hip/hip_runtime.h>

// IntersiteModel fused kernel — fp32 vector, round 4.
// 1 thread = 1 sample. Per-thread scratch in LDS (feature-major, f*128+tid),
// 80 features * 4B * 128 thr = 40960 B/block -> exactly 4 blocks/CU.
//   staging:  f 0..15 x0 | f 16..39 x1[u][i] | f 40..55 y0 | f 56..79 y1[v][i]
//   stage1+:  f 0..31 t0 | f 32..79 t1[u][i]
//   stage3:   f 0..31 s  | f 32..63 v_i (one xyz component at a time)  <= 80 OK
//
// Round-4 change (post-mortem of round 3): rocprof showed VGPR_Count=128 with
// WRITE_SIZE=302MB (output is 1.6MB) -> the allocator targeted 4 waves/EU and
// spilled ~300MB/launch of accumulators to scratch, even though LDS
// (320B/thread) pins occupancy at 2 waves/SIMD regardless. Pin the allocator
// to exactly 2 waves/EU via amdgpu_waves_per_eu(2,2) so it gets the full
// 256-VGPR budget; stage-2 peak live set (~190 floats) then fits with zero
// spill. Loop structure unchanged from round 3:
//   * #pragma unroll 2/4 on weight-contraction loops (pipeline s_loads)
//   * merged W1_11_0+W1_11_1 one uv loop; merged W2_10+W2_11_1+W2_11_0 one
//     u loop (shares LDS reads); W2_01 runs before u0 exists.

#define TPB 128

__device__ __forceinline__ float sigf(float x) {
    return 1.0f / (1.0f + __expf(-x));
}

__global__ __launch_bounds__(TPB)
__attribute__((amdgpu_waves_per_eu(2, 2)))
void intersite_fused(const float* __restrict__ site1,
                     const float* __restrict__ site2,
                     const float* __restrict__ edge,
                     const float* __restrict__ W1_00,
                     const float* __restrict__ W1_11_0,
                     const float* __restrict__ W1_01,
                     const float* __restrict__ W1_10,
                     const float* __restrict__ W1_11_1,
                     const float* __restrict__ W2_00,
                     const float* __restrict__ W2_11_0,
                     const float* __restrict__ W2_01,
                     const float* __restrict__ W2_10,
                     const float* __restrict__ W2_11_1,
                     const float* __restrict__ W3_00,
                     const float* __restrict__ W3_11,
                     float* __restrict__ out, int B)
{
    __shared__ float lds[80 * TPB];
    const int t = threadIdx.x;
    const int b = blockIdx.x * TPB + t;
    if (b >= B) return;   // no barriers anywhere -> early return is safe

#define LDSF(f) lds[(f) * TPB + t]

    const float inv_s3   = 0.57735026918962576f;  // 1/sqrt(3)
    const float inv_s2   = 0.70710678118654752f;  // 1/sqrt(2)
    const float inv_s320 = 0.05590169943749474f;  // 1/sqrt(320)
    const float inv_s192 = 0.07216878364870323f;  // 1/sqrt(192)
    const float inv_s256 = 0.0625f;               // 1/sqrt(256)
    const float inv_s2048= 0.02209708691207961f;  // 1/sqrt(2048)

    // ---------------- stage inputs into LDS ----------------
    {
        const float4* p1 = (const float4*)(site1 + (size_t)b * 40);
        #pragma unroll
        for (int q = 0; q < 10; ++q) {
            float4 r = p1[q];
            LDSF(q*4+0) = r.x; LDSF(q*4+1) = r.y;
            LDSF(q*4+2) = r.z; LDSF(q*4+3) = r.w;
        }
        const float4* p2 = (const float4*)(site2 + (size_t)b * 40);
        #pragma unroll
        for (int q = 0; q < 10; ++q) {
            float4 r = p2[q];
            LDSF(40+q*4+0) = r.x; LDSF(40+q*4+1) = r.y;
            LDSF(40+q*4+2) = r.z; LDSF(40+q*4+3) = r.w;
        }
    }
    // edge stays in registers (accessed only with unrolled v<=4 loops)
    float e0[4], e1[12];
    {
        const float4* pe = (const float4*)(edge + (size_t)b * 16);
        float4 r0 = pe[0], r1 = pe[1], r2 = pe[2], r3 = pe[3];
        e0[0]=r0.x; e0[1]=r0.y; e0[2]=r0.z; e0[3]=r0.w;
        e1[0]=r1.x; e1[1]=r1.y; e1[2]=r1.z; e1[3]=r1.w;
        e1[4]=r2.x; e1[5]=r2.y; e1[6]=r2.z; e1[7]=r2.w;
        e1[8]=r3.x; e1[9]=r3.y; e1[10]=r3.z; e1[11]=r3.w;
    }

    // ---------------- stage 1: (x,y) -> t0[32], t1[16][3] ----------------
    float t0[32];
    #pragma unroll
    for (int k = 0; k < 32; ++k) t0[k] = 0.0f;
    float t1[48];
    #pragma unroll
    for (int j = 0; j < 48; ++j) t1[j] = 0.0f;

    // W1_00 (16,16,32): sum_{u,v} x0[u] y0[v] W[u,v,w]
    #pragma unroll 1
    for (int u = 0; u < 16; ++u) {
        float xu = LDSF(u);
        const float* wu = W1_00 + u * 512;           // u*16*32
        #pragma unroll 4
        for (int v = 0; v < 16; ++v) {
            float f = xu * LDSF(40 + v);
            const float* w = wu + v * 32;
            #pragma unroll
            for (int k = 0; k < 32; ++k) t0[k] = fmaf(f, w[k], t0[k]);
        }
    }

    // merged W1_11_0 (8,8,32) + W1_11_1 (8,8,16): shares x1/y1 LDS reads.
    //   t0[w] += (x1[u].y1[v])/sqrt3 * W0[u,v,w]
    //   t1[w,i] += (x1[u] x y1[v])_i / sqrt2 * W1[u,v,w]
    #pragma unroll 2
    for (int uv = 0; uv < 64; ++uv) {
        int u = uv >> 3, v = uv & 7;
        float ax = LDSF(16+u*3), ay = LDSF(17+u*3), az = LDSF(18+u*3);
        float bx = LDSF(56+v*3), by = LDSF(57+v*3), bz = LDSF(58+v*3);
        float d = ax*bx;
        d = fmaf(ay, by, d);
        d = fmaf(az, bz, d);
        d *= inv_s3;
        const float* w0 = W1_11_0 + uv * 32;
        #pragma unroll
        for (int k = 0; k < 32; ++k) t0[k] = fmaf(d, w0[k], t0[k]);
        float cx = (ay*bz - az*by) * inv_s2;
        float cy = (az*bx - ax*bz) * inv_s2;
        float cz = (ax*by - ay*bx) * inv_s2;
        const float* w1 = W1_11_1 + uv * 16;
        #pragma unroll
        for (int k = 0; k < 16; ++k) {
            t1[k*3+0] = fmaf(cx, w1[k], t1[k*3+0]);
            t1[k*3+1] = fmaf(cy, w1[k], t1[k*3+1]);
            t1[k*3+2] = fmaf(cz, w1[k], t1[k*3+2]);
        }
    }
    #pragma unroll
    for (int k = 0; k < 32; ++k) t0[k] *= inv_s320;

    // W1_01 (16,8,16) factored: A[v,w] = sum_u x0[u] W[u,v,w]; t1 += A y1
    {
        float yr[24];
        #pragma unroll
        for (int v = 0; v < 8; ++v)
            #pragma unroll
            for (int i = 0; i < 3; ++i) yr[v*3+i] = LDSF(56 + v*3 + i);
        #pragma unroll            // FULL unroll: keeps t1 indices constant
        for (int wc = 0; wc < 2; ++wc) {      // w-chunks of 8
            float A[64];
            #pragma unroll
            for (int j = 0; j < 64; ++j) A[j] = 0.0f;
            #pragma unroll 2
            for (int u = 0; u < 16; ++u) {
                float xu = LDSF(u);
                const float* w = W1_01 + u*128 + wc*8;   // u*128 + v*16 + w
                #pragma unroll
                for (int v = 0; v < 8; ++v)
                    #pragma unroll
                    for (int k = 0; k < 8; ++k)
                        A[v*8+k] = fmaf(xu, w[v*16+k], A[v*8+k]);
            }
            #pragma unroll
            for (int v = 0; v < 8; ++v)
                #pragma unroll
                for (int k = 0; k < 8; ++k)
                    #pragma unroll
                    for (int i = 0; i < 3; ++i)
                        t1[(wc*8+k)*3+i] = fmaf(A[v*8+k], yr[v*3+i], t1[(wc*8+k)*3+i]);
        }
    }
    // W1_10 (8,16,16) factored: Bm[u,w] = sum_v y0[v] W[u,v,w]; t1 += Bm x1
    {
        float xr[24];
        #pragma unroll
        for (int u = 0; u < 8; ++u)
            #pragma unroll
            for (int i = 0; i < 3; ++i) xr[u*3+i] = LDSF(16 + u*3 + i);
        #pragma unroll            // FULL unroll
        for (int wc = 0; wc < 2; ++wc) {
            float Bm[64];
            #pragma unroll
            for (int j = 0; j < 64; ++j) Bm[j] = 0.0f;
            #pragma unroll 2
            for (int v = 0; v < 16; ++v) {
                float yv = LDSF(40 + v);
                const float* w = W1_10 + v*16 + wc*8;    // u*256 + v*16 + w
                #pragma unroll
                for (int u = 0; u < 8; ++u)
                    #pragma unroll
                    for (int k = 0; k < 8; ++k)
                        Bm[u*8+k] = fmaf(yv, w[u*256+k], Bm[u*8+k]);
            }
            #pragma unroll
            for (int u = 0; u < 8; ++u)
                #pragma unroll
                for (int k = 0; k < 8; ++k)
                    #pragma unroll
                    for (int i = 0; i < 3; ++i)
                        t1[(wc*8+k)*3+i] = fmaf(Bm[u*8+k], xr[u*3+i], t1[(wc*8+k)*3+i]);
        }
    }
    #pragma unroll
    for (int j = 0; j < 48; ++j) t1[j] *= inv_s320;

    // spill t into LDS (x/y region dead): f 0..31 = t0, f 32..79 = t1
    #pragma unroll
    for (int k = 0; k < 32; ++k) LDSF(k) = t0[k];
    #pragma unroll
    for (int j = 0; j < 48; ++j) LDSF(32 + j) = t1[j];

    // ---------------- stage 2: (t,e) -> u0[64], u1[32][3] ----------------
    float u1[96];
    #pragma unroll
    for (int j = 0; j < 96; ++j) u1[j] = 0.0f;

    // W2_01 (32,4,32) factored: A2[v,w] = sum_u t0[u] W[u,v,w]; u1 += A2 e1
    // (runs BEFORE u0 exists, so A2's 64 regs don't stack on u0's 64)
    #pragma unroll                // FULL unroll
    for (int wc = 0; wc < 2; ++wc) {          // w-chunks of 16
        float A2[64];
        #pragma unroll
        for (int j = 0; j < 64; ++j) A2[j] = 0.0f;
        #pragma unroll 2
        for (int u = 0; u < 32; ++u) {
            float tu = LDSF(u);
            const float* w = W2_01 + u*128 + wc*16;      // u*128 + v*32 + w
            #pragma unroll
            for (int v = 0; v < 4; ++v)
                #pragma unroll
                for (int k = 0; k < 16; ++k)
                    A2[v*16+k] = fmaf(tu, w[v*32+k], A2[v*16+k]);
        }
        #pragma unroll
        for (int v = 0; v < 4; ++v)
            #pragma unroll
            for (int k = 0; k < 16; ++k)
                #pragma unroll
                for (int i = 0; i < 3; ++i)
                    u1[(wc*16+k)*3+i] = fmaf(A2[v*16+k], e1[v*3+i], u1[(wc*16+k)*3+i]);
    }

    float u0[64];
    #pragma unroll
    for (int k = 0; k < 64; ++k) u0[k] = 0.0f;

    // merged W2_10 (16,4,32) + W2_11_1 (16,4,32) + W2_11_0 (16,4,64):
    // shares the 3 t1[u] LDS reads across all three contractions.
    #pragma unroll 1
    for (int u = 0; u < 16; ++u) {
        float ax = LDSF(32+u*3), ay = LDSF(33+u*3), az = LDSF(34+u*3);
        #pragma unroll
        for (int v = 0; v < 4; ++v) {
            float ev = e0[v];
            float f0 = ax*ev, f1 = ay*ev, f2 = az*ev;
            const float* wa = W2_10 + u*128 + v*32;
            #pragma unroll
            for (int k = 0; k < 32; ++k) {
                u1[k*3+0] = fmaf(f0, wa[k], u1[k*3+0]);
                u1[k*3+1] = fmaf(f1, wa[k], u1[k*3+1]);
                u1[k*3+2] = fmaf(f2, wa[k], u1[k*3+2]);
            }
            float bx = e1[v*3], by = e1[v*3+1], bz = e1[v*3+2];
            float cx = (ay*bz - az*by) * inv_s2;
            float cy = (az*bx - ax*bz) * inv_s2;
            float cz = (ax*by - ay*bx) * inv_s2;
            const float* wb = W2_11_1 + u*128 + v*32;
            #pragma unroll
            for (int k = 0; k < 32; ++k) {
                u1[k*3+0] = fmaf(cx, wb[k], u1[k*3+0]);
                u1[k*3+1] = fmaf(cy, wb[k], u1[k*3+1]);
                u1[k*3+2] = fmaf(cz, wb[k], u1[k*3+2]);
            }
            float dd = ax*bx;
            dd = fmaf(ay, by, dd);
            dd = fmaf(az, bz, dd);
            dd *= inv_s3;
            const float* wc = W2_11_0 + u*256 + v*64;
            #pragma unroll
            for (int k = 0; k < 64; ++k) u0[k] = fmaf(dd, wc[k], u0[k]);
        }
    }
    // W2_00 (32,4,64): u0[w] += t0[u] e0[v] W[u,v,w]
    #pragma unroll 2
    for (int u = 0; u < 32; ++u) {
        float tu = LDSF(u);
        #pragma unroll
        for (int v = 0; v < 4; ++v) {
            float f = tu * e0[v];
            const float* w = W2_00 + u*256 + v*64;
            #pragma unroll
            for (int k = 0; k < 64; ++k) u0[k] = fmaf(f, w[k], u0[k]);
        }
    }
    #pragma unroll
    for (int k = 0; k < 64; ++k) u0[k] *= inv_s192;
    #pragma unroll
    for (int j = 0; j < 96; ++j) u1[j] *= inv_s256;

    // ---------------- stage 3: gate + tensor square ----------------
    // s = silu(u0[:32]) -> LDS f 0..31 (t0 region dead)
    #pragma unroll
    for (int k = 0; k < 32; ++k) {
        float x = u0[k];
        LDSF(k) = x * sigf(x);
    }
    // v = u1 * sigmoid(u0[32:]) kept in registers (const-indexed)
    #pragma unroll
    for (int wv = 0; wv < 32; ++wv) {
        float gw = sigf(u0[32 + wv]);
        u1[wv*3+0] *= gw;  u1[wv*3+1] *= gw;  u1[wv*3+2] *= gw;
    }

    float acc0 = 0.0f, acc1 = 0.0f;
    // scalar part: acc0 = sum_{u,v2} s[u] s[v2] W3_00[u,v2]
    {
        float zs[32];
        #pragma unroll
        for (int k = 0; k < 32; ++k) zs[k] = 0.0f;
        #pragma unroll 2
        for (int u = 0; u < 32; ++u) {
            float su = LDSF(u);
            const float* wa = W3_00 + u*32;
            #pragma unroll
            for (int k = 0; k < 32; ++k) zs[k] = fmaf(su, wa[k], zs[k]);
        }
        #pragma unroll
        for (int k = 0; k < 32; ++k) acc0 = fmaf(zs[k], LDSF(k), acc0);
    }
    // vector part, ONE COMPONENT AT A TIME through LDS f 32..63 (bounds-safe):
    // acc1 = sum_i sum_{u,v2} v[u,i] v[v2,i] W3_11[u,v2]
    #pragma unroll
    for (int i = 0; i < 3; ++i) {
        #pragma unroll
        for (int wv = 0; wv < 32; ++wv) LDSF(32 + wv) = u1[wv*3 + i];
        float zv[32];
        #pragma unroll
        for (int k = 0; k < 32; ++k) zv[k] = 0.0f;
        #pragma unroll 2
        for (int u = 0; u < 32; ++u) {
            float vu = LDSF(32 + u);
            const float* wb = W3_11 + u*32;
            #pragma unroll
            for (int k = 0; k < 32; ++k) zv[k] = fmaf(vu, wb[k], zv[k]);
        }
        #pragma unroll
        for (int k = 0; k < 32; ++k) acc1 = fmaf(zv[k], LDSF(32 + k), acc1);
    }

    out[b] = (acc0 + acc1 * inv_s3) * inv_s2048;
#undef LDSF
}

extern "C" void kernel_launch(void* const* d_in, const int* in_sizes, int n_in,
                              void* d_out, int out_size, void* d_ws, size_t ws_size,
                              hipStream_t stream)
{
    const float* site1   = (const float*)d_in[0];
    const float* site2   = (const float*)d_in[1];
    const float* edge    = (const float*)d_in[2];
    const float* W1_00   = (const float*)d_in[3];
    const float* W1_11_0 = (const float*)d_in[4];
    const float* W1_01   = (const float*)d_in[5];
    const float* W1_10   = (const float*)d_in[6];
    const float* W1_11_1 = (const float*)d_in[7];
    const float* W2_00   = (const float*)d_in[8];
    const float* W2_11_0 = (const float*)d_in[9];
    const float* W2_01   = (const float*)d_in[10];
    const float* W2_10   = (const float*)d_in[11];
    const float* W2_11_1 = (const float*)d_in[12];
    const float* W3_00   = (const float*)d_in[13];
    const float* W3_11   = (const float*)d_in[14];
    float* out = (float*)d_out;

    const int B = in_sizes[0] / 40;
    dim3 grid((B + TPB - 1) / TPB), block(TPB);
    hipLaunchKernelGGL(intersite_fused, grid, block, 0, stream,
                       site1, site2, edge,
                       W1_00, W1_11_0, W1_01, W1_10, W1_11_1,
                       W2_00, W2_11_0, W2_01, W2_10, W2_11_1,
                       W3_00, W3_11, out, B);
}